// Round 2
// baseline (332.364 us; speedup 1.0000x reference)
//
#include <hip/hip_runtime.h>

typedef unsigned short u16;
typedef unsigned int u32;
typedef __attribute__((ext_vector_type(8))) short bf16x8;   // 8 bf16 = 4 VGPRs
typedef __attribute__((ext_vector_type(4))) float f32x4;
typedef __attribute__((ext_vector_type(16))) float f32x16;
typedef __attribute__((ext_vector_type(4))) float floatx4;
typedef __attribute__((ext_vector_type(4))) u16 u16x4;

__device__ __forceinline__ u16 f2bf(float x) {
  union { float f; u32 u; } c; c.f = x;
  return (u16)((c.u + 0x7fffu + ((c.u >> 16) & 1u)) >> 16);  // RNE
}
__device__ __forceinline__ u32 packbf(float a, float b) {
  return (u32)f2bf(a) | ((u32)f2bf(b) << 16);
}
__device__ __forceinline__ u32 cvtpk(float lo, float hi) {
  u32 r;
  asm("v_cvt_pk_bf16_f32 %0, %1, %2" : "=v"(r) : "v"(lo), "v"(hi));
  return r;
}
__device__ __forceinline__ float bf2f(u16 v) {
  union { u32 u; float f; } c; c.u = (u32)v << 16; return c.f;
}

__device__ __forceinline__ void gload16(const u16* g, u16* l) {
  auto gp = (const __attribute__((address_space(1))) unsigned int*)g;
  auto lp = (__attribute__((address_space(3))) unsigned int*)l;
  __builtin_amdgcn_global_load_lds(gp, lp, 16, 0, 0);
}

// ---------------- fp32 -> bf16: all 7 tensors in one launch ------------------
__global__ void cvt7(const float* s0, const float* s1, const float* s2,
                     const float* s3, const float* s4, const float* s5, const float* s6,
                     u16* d0, u16* d1, u16* d2, u16* d3, u16* d4, u16* d5, u16* d6) {
  const int y = blockIdx.y;
  const float* s = (y == 0) ? s0 : (y == 1) ? s1 : (y == 2) ? s2 : (y == 3) ? s3
                  : (y == 4) ? s4 : (y == 5) ? s5 : s6;
  u16* d = (y == 0) ? d0 : (y == 1) ? d1 : (y == 2) ? d2 : (y == 3) ? d3
          : (y == 4) ? d4 : (y == 5) ? d5 : d6;
  const int n4 = (y < 3) ? (1 << 20) : (1 << 18);
  int i = blockIdx.x * 256 + threadIdx.x;
  if (i < n4) {
    floatx4 v = ((const floatx4*)s)[i];
    u16x4 o;
    o.x = f2bf(v.x); o.y = f2bf(v.y); o.z = f2bf(v.z); o.w = f2bf(v.w);
    ((u16x4*)d)[i] = o;
  }
}

// ---------------- batched 128x128 projection GEMM, C = A @ W^T + b -----------
// z=0: Q (scaled by 1/sqrt(64)*log2e), z=1: K  -> [N][H][2048][64]
// z=2: V -> transposed [N][H][64][2048]
__global__ __launch_bounds__(256) void gemm3(const u16* A0, const u16* A1, const u16* A2,
                                             const u16* W0, const u16* W1, const u16* W2,
                                             const float* b0, const float* b1, const float* b2,
                                             u16* o0, u16* o1, u16* o2) {
  __shared__ u16 lA[128 * 32];
  __shared__ u16 lB[128 * 32];
  const int z = blockIdx.z;
  const u16* A  = (z == 0) ? A0 : (z == 1) ? A1 : A2;
  const u16* Bw = (z == 0) ? W0 : (z == 1) ? W1 : W2;
  const float* bias = (z == 0) ? b0 : (z == 1) ? b1 : b2;
  u16* outp = (z == 0) ? o0 : (z == 1) ? o1 : o2;
  const float scl = (z == 0) ? (0.125f * 1.44269504089f) : 1.0f;

  const int tid = threadIdx.x;
  const int brow = blockIdx.y * 128, bcol = blockIdx.x * 128;
  const int lane = tid & 63, w = tid >> 6;
  const int wr = w >> 1, wc = w & 1;
  const int fr = lane & 15, fq = lane >> 4;
  f32x4 acc[4][4] = {};

  for (int k0 = 0; k0 < 1024; k0 += 32) {
    __syncthreads();
#pragma unroll
    for (int it = 0; it < 2; ++it) {
      int chunk = tid + it * 256;
      int row = chunk >> 2;
      int col = (chunk & 3) * 8;
      gload16(A  + (size_t)(brow + row) * 1024 + k0 + col, &lA[chunk * 8]);
      gload16(Bw + (size_t)(bcol + row) * 1024 + k0 + col, &lB[chunk * 8]);
    }
    __syncthreads();
    bf16x8 af[4], bfr[4];
#pragma unroll
    for (int m = 0; m < 4; ++m) af[m]  = *(const bf16x8*)&lA[(wr * 64 + m * 16 + fr) * 32 + fq * 8];
#pragma unroll
    for (int n = 0; n < 4; ++n) bfr[n] = *(const bf16x8*)&lB[(wc * 64 + n * 16 + fr) * 32 + fq * 8];
#pragma unroll
    for (int m = 0; m < 4; ++m)
#pragma unroll
      for (int n = 0; n < 4; ++n)
        acc[m][n] = __builtin_amdgcn_mfma_f32_16x16x32_bf16(af[m], bfr[n], acc[m][n], 0, 0, 0);
  }

#pragma unroll
  for (int m = 0; m < 4; ++m) {
#pragma unroll
    for (int n = 0; n < 4; ++n) {
      int colg = bcol + wc * 64 + n * 16 + fr;
      float bv = bias[colg];
#pragma unroll
      for (int j = 0; j < 4; ++j) {
        int rowg = brow + wr * 64 + m * 16 + fq * 4 + j;
        float v = (acc[m][n][j] + bv) * scl;
        int nb = rowg >> 11, l = rowg & 2047;
        int h = colg >> 6, dd = colg & 63;
        size_t idx = (z < 2) ? (((size_t)(nb * 16 + h) * 2048 + l) * 64 + dd)
                             : (((size_t)(nb * 16 + h) * 64 + dd) * 2048 + l);
        outp[idx] = f2bf(v);
      }
    }
  }
}

// ---------------- out-projection GEMM (f32 out) ------------------------------
__global__ __launch_bounds__(256) void gemm_o(const u16* __restrict__ A,
                                              const u16* __restrict__ Bw,
                                              const float* __restrict__ bias,
                                              float* __restrict__ outp) {
  __shared__ u16 lA[128 * 32];
  __shared__ u16 lB[128 * 32];
  const int tid = threadIdx.x;
  const int brow = blockIdx.y * 128, bcol = blockIdx.x * 128;
  const int lane = tid & 63, w = tid >> 6;
  const int wr = w >> 1, wc = w & 1;
  const int fr = lane & 15, fq = lane >> 4;
  f32x4 acc[4][4] = {};

  for (int k0 = 0; k0 < 1024; k0 += 32) {
    __syncthreads();
#pragma unroll
    for (int it = 0; it < 2; ++it) {
      int chunk = tid + it * 256;
      int row = chunk >> 2;
      int col = (chunk & 3) * 8;
      gload16(A  + (size_t)(brow + row) * 1024 + k0 + col, &lA[chunk * 8]);
      gload16(Bw + (size_t)(bcol + row) * 1024 + k0 + col, &lB[chunk * 8]);
    }
    __syncthreads();
    bf16x8 af[4], bfr[4];
#pragma unroll
    for (int m = 0; m < 4; ++m) af[m]  = *(const bf16x8*)&lA[(wr * 64 + m * 16 + fr) * 32 + fq * 8];
#pragma unroll
    for (int n = 0; n < 4; ++n) bfr[n] = *(const bf16x8*)&lB[(wc * 64 + n * 16 + fr) * 32 + fq * 8];
#pragma unroll
    for (int m = 0; m < 4; ++m)
#pragma unroll
      for (int n = 0; n < 4; ++n)
        acc[m][n] = __builtin_amdgcn_mfma_f32_16x16x32_bf16(af[m], bfr[n], acc[m][n], 0, 0, 0);
  }

#pragma unroll
  for (int m = 0; m < 4; ++m) {
#pragma unroll
    for (int n = 0; n < 4; ++n) {
      int colg = bcol + wc * 64 + n * 16 + fr;
      float bv = bias[colg];
#pragma unroll
      for (int j = 0; j < 4; ++j) {
        int rowg = brow + wr * 64 + m * 16 + fq * 4 + j;
        outp[(size_t)rowg * 1024 + colg] = acc[m][n][j] + bv;
      }
    }
  }
}

// ---------------- causal flash attention, split-KV=2 -------------------------
// Q,K: [NH=32][2048][64] bf16 (Q pre-scaled by 1/sqrt(64)*log2e); V^T: [NH][64][2048].
// Each wave: one (q-tile t of 32 rows, split half). Writes UNNORMALIZED partial
// acc (bf16, [part][q(32)][d(64)]) + m,l (f32 [part][32]).
__global__ __launch_bounds__(256) void attn_part(const u16* __restrict__ Qp,
                                                 const u16* __restrict__ Kp,
                                                 const u16* __restrict__ Vt,
                                                 u16* __restrict__ accP,
                                                 float* __restrict__ mP,
                                                 float* __restrict__ lP) {
  const int lane = threadIdx.x & 63, w = threadIdx.x >> 6;
  const int nh = blockIdx.y;
  const int job = blockIdx.x * 4 + w;          // [0,128)
  const int t = job >> 1, sp = job & 1;
  const int q0 = t * 32;
  const int col = lane & 31, hi = lane >> 5;
  const u16* Q = Qp + (size_t)nh * 2048 * 64;
  const u16* K = Kp + (size_t)nh * 2048 * 64;
  const u16* V = Vt + (size_t)nh * 64 * 2048;
  const int q = q0 + col;

  bf16x8 qf[4];
#pragma unroll
  for (int ks = 0; ks < 4; ++ks) qf[ks] = *(const bf16x8*)&Q[(size_t)q * 64 + ks * 16 + hi * 8];

  const int nIter = t + 1;
  const int half = (nIter + 1) >> 1;
  const int i0 = sp ? half : 0;
  const int i1 = sp ? nIter : half;

  f32x16 acc0 = {}, acc1 = {};   // out^T tiles: d in [0,32) and [32,64)
  float mrow = -1e30f, lrow = 0.f;

  for (int i = i0; i < i1; ++i) {
    const int s0 = i * 32;
    f32x16 sc = {};
    __builtin_amdgcn_s_setprio(1);
#pragma unroll
    for (int ks = 0; ks < 4; ++ks) {
      bf16x8 kf = *(const bf16x8*)&K[(size_t)(s0 + col) * 64 + ks * 16 + hi * 8];
      sc = __builtin_amdgcn_mfma_f32_32x32x16_bf16(kf, qf[ks], sc, 0, 0, 0);
    }
    __builtin_amdgcn_s_setprio(0);
    // lane holds S^T[s][q] for q=col: s-rows sr=(r&3)+8*(r>>2)+4*hi
    float pr[16];
    float pmax = -1e30f;
    const bool diag = (i == t);
#pragma unroll
    for (int r = 0; r < 16; ++r) {
      int sr = (r & 3) + 8 * (r >> 2) + 4 * hi;
      float v = sc[r];
      if (diag && sr > col) v = -1e30f;            // causal mask on diagonal tile
      pr[r] = v;
      pmax = fmaxf(pmax, v);
    }
    pmax = fmaxf(pmax, __shfl_xor(pmax, 32));
    // defer-max: rescale only when the running max grew by >8 (base-2 units)
    if (!__all(pmax <= mrow + 8.f)) {
      float mnew = fmaxf(mrow, pmax);
      float alpha = exp2f(mrow - mnew);
#pragma unroll
      for (int r = 0; r < 16; ++r) { acc0[r] *= alpha; acc1[r] *= alpha; }
      lrow *= alpha;
      mrow = mnew;
    }
    float ps = 0.f;
#pragma unroll
    for (int r = 0; r < 16; ++r) { float p = exp2f(pr[r] - mrow); pr[r] = p; ps += p; }
    ps += __shfl_xor(ps, 32);
    lrow += ps;

    // Build PV B-operand (P^T as s x q), exchanging halves with lane^32
#pragma unroll
    for (int ks = 0; ks < 2; ++ks) {
      u32 A0 = cvtpk(pr[8 * ks + 0], pr[8 * ks + 1]);
      u32 A1 = cvtpk(pr[8 * ks + 2], pr[8 * ks + 3]);
      u32 B0 = cvtpk(pr[8 * ks + 4], pr[8 * ks + 5]);
      u32 B1 = cvtpk(pr[8 * ks + 6], pr[8 * ks + 7]);
      u32 t0 = __shfl_xor(hi ? A0 : B0, 32);
      u32 t1 = __shfl_xor(hi ? A1 : B1, 32);
      union { u32 u[4]; bf16x8 v; } pf;
      pf.u[0] = hi ? t0 : A0;
      pf.u[1] = hi ? t1 : A1;
      pf.u[2] = hi ? B0 : t0;
      pf.u[3] = hi ? B1 : t1;
      bf16x8 vf0 = *(const bf16x8*)&V[(size_t)(col) * 2048 + s0 + ks * 16 + hi * 8];
      bf16x8 vf1 = *(const bf16x8*)&V[(size_t)(32 + col) * 2048 + s0 + ks * 16 + hi * 8];
      __builtin_amdgcn_s_setprio(1);
      acc0 = __builtin_amdgcn_mfma_f32_32x32x16_bf16(vf0, pf.v, acc0, 0, 0, 0);
      acc1 = __builtin_amdgcn_mfma_f32_32x32x16_bf16(vf1, pf.v, acc1, 0, 0, 0);
      __builtin_amdgcn_s_setprio(0);
    }
  }

  // write unnormalized partial: acc [part][q=col][d], m/l [part][q]
  const int part = (nh * 64 + t) * 2 + sp;
  u16* base = accP + (size_t)part * 2048 + col * 64;
#pragma unroll
  for (int rp = 0; rp < 8; ++rp) {
    int r = rp * 2;
    int d = (r & 3) + 8 * (r >> 2) + 4 * hi;
    *(u32*)&base[d]      = packbf(acc0[r], acc0[r + 1]);
    *(u32*)&base[32 + d] = packbf(acc1[r], acc1[r + 1]);
  }
  if (hi == 0) {
    mP[part * 32 + col] = mrow;
    lP[part * 32 + col] = lrow;
  }
}

// ---------------- combine split-KV partials -> attn matrix -------------------
// attn out: [N][2048][1024] bf16 (head-concat layout for the out projection)
__global__ void combine2(const u16* __restrict__ accP, const float* __restrict__ mP,
                         const float* __restrict__ lP, u16* __restrict__ at) {
  const int T = blockIdx.x;              // [0,2048): nh*64 + t
  const int nh = T >> 6, t = T & 63;
  const int q = threadIdx.x >> 3;        // [0,32)
  const int d0 = (threadIdx.x & 7) * 8;  // [0,64) step 8
  const size_t pA = (size_t)T * 2, pB = pA + 1;
  const float mA = mP[pA * 32 + q], mB = mP[pB * 32 + q];
  const float lA = lP[pA * 32 + q], lB = lP[pB * 32 + q];
  const float m = fmaxf(mA, mB);
  float wA = exp2f(mA - m), wB = exp2f(mB - m);
  const float inv = 1.f / (lA * wA + lB * wB);
  wA *= inv; wB *= inv;
  const bf16x8 a = *(const bf16x8*)&accP[pA * 2048 + q * 64 + d0];
  const bf16x8 b = *(const bf16x8*)&accP[pB * 2048 + q * 64 + d0];
  const int nb = nh >> 4, h = nh & 15;
  u16* o = &at[((size_t)(nb * 2048 + t * 32 + q)) * 1024 + h * 64 + d0];
#pragma unroll
  for (int j = 0; j < 4; ++j) {
    float v0 = bf2f((u16)a[2 * j])     * wA + bf2f((u16)b[2 * j])     * wB;
    float v1 = bf2f((u16)a[2 * j + 1]) * wA + bf2f((u16)b[2 * j + 1]) * wB;
    *(u32*)&o[2 * j] = packbf(v0, v1);
  }
}

// -----------------------------------------------------------------------------
extern "C" void kernel_launch(void* const* d_in, const int* in_sizes, int n_in,
                              void* d_out, int out_size, void* d_ws, size_t ws_size,
                              hipStream_t stream) {
  const float* queries = (const float*)d_in[0];
  const float* keys    = (const float*)d_in[1];
  const float* values  = (const float*)d_in[2];
  const float* Wq = (const float*)d_in[3]; const float* bq = (const float*)d_in[4];
  const float* Wk = (const float*)d_in[5]; const float* bk = (const float*)d_in[6];
  const float* Wv = (const float*)d_in[7]; const float* bv = (const float*)d_in[8];
  const float* Wo = (const float*)d_in[9]; const float* bo = (const float*)d_in[10];
  float* out = (float*)d_out;
  char* ws = (char*)d_ws;

  const size_t MB = 1u << 20;
  u16* xq  = (u16*)(ws + 0 * MB);    // 8 MB (reused as attn output `at`)
  u16* xk  = (u16*)(ws + 8 * MB);
  u16* xv  = (u16*)(ws + 16 * MB);
  u16* wqb = (u16*)(ws + 24 * MB);
  u16* wkb = (u16*)(ws + 26 * MB);
  u16* wvb = (u16*)(ws + 28 * MB);
  u16* wob = (u16*)(ws + 30 * MB);
  u16* qp  = (u16*)(ws + 32 * MB);
  u16* kp  = (u16*)(ws + 40 * MB);
  u16* vt  = (u16*)(ws + 48 * MB);
  u16* at  = xq;                            // attn out reuses xq
  // split-KV partials (reuse xk/xv: dead after projections; wqb/wkb for m,l)
  u16*   accP = (u16*)(ws + 8 * MB);        // 4096 parts x 4KB = 16 MB
  float* mPp  = (float*)(ws + 24 * MB);     // 512 KB
  float* lPp  = (float*)(ws + 24 * MB + 512 * 1024);

  // fp32 -> bf16 (all tensors, one launch)
  cvt7<<<dim3(4096, 7), 256, 0, stream>>>(queries, keys, values, Wq, Wk, Wv, Wo,
                                          xq, xk, xv, wqb, wkb, wvb, wob);
  // Q/K/V projections, one batched launch (768 blocks = 3/CU)
  gemm3<<<dim3(8, 32, 3), 256, 0, stream>>>(xq, xk, xv, wqb, wkb, wvb,
                                            bq, bk, bv, qp, kp, vt);
  // attention partials (4096 balanced waves) + combine
  attn_part<<<dim3(32, 32), 256, 0, stream>>>(qp, kp, vt, accP, mPp, lPp);
  combine2<<<2048, 256, 0, stream>>>(accP, mPp, lPp, at);
  // output projection
  gemm_o<<<dim3(8, 32), 256, 0, stream>>>(at, wob, bo, out);
}

// Round 4
// 284.136 us; speedup vs baseline: 1.1697x; 1.1697x over previous
//
#include <hip/hip_runtime.h>

typedef unsigned short u16;
typedef unsigned int u32;
typedef __attribute__((ext_vector_type(8))) short bf16x8;   // 8 bf16 = 4 VGPRs
typedef __attribute__((ext_vector_type(4))) float f32x4;
typedef __attribute__((ext_vector_type(16))) float f32x16;
typedef __attribute__((ext_vector_type(4))) float floatx4;
typedef __attribute__((ext_vector_type(4))) u16 u16x4;

__device__ __forceinline__ u16 f2bf(float x) {
  union { float f; u32 u; } c; c.f = x;
  return (u16)((c.u + 0x7fffu + ((c.u >> 16) & 1u)) >> 16);  // RNE
}
__device__ __forceinline__ u32 packbf(float a, float b) {
  return (u32)f2bf(a) | ((u32)f2bf(b) << 16);
}
__device__ __forceinline__ u32 cvtpk(float lo, float hi) {
  u32 r;
  asm("v_cvt_pk_bf16_f32 %0, %1, %2" : "=v"(r) : "v"(lo), "v"(hi));
  return r;
}
__device__ __forceinline__ float bf2f(u16 v) {
  union { u32 u; float f; } c; c.u = (u32)v << 16; return c.f;
}

__device__ __forceinline__ void gload16(const u16* g, u16* l) {
  auto gp = (const __attribute__((address_space(1))) unsigned int*)g;
  auto lp = (__attribute__((address_space(3))) unsigned int*)l;
  __builtin_amdgcn_global_load_lds(gp, lp, 16, 0, 0);
}

// ---------------- fp32 -> bf16: all 7 tensors in one launch ------------------
__global__ void cvt7(const float* s0, const float* s1, const float* s2,
                     const float* s3, const float* s4, const float* s5, const float* s6,
                     u16* d0, u16* d1, u16* d2, u16* d3, u16* d4, u16* d5, u16* d6) {
  const int y = blockIdx.y;
  const float* s = (y == 0) ? s0 : (y == 1) ? s1 : (y == 2) ? s2 : (y == 3) ? s3
                  : (y == 4) ? s4 : (y == 5) ? s5 : s6;
  u16* d = (y == 0) ? d0 : (y == 1) ? d1 : (y == 2) ? d2 : (y == 3) ? d3
          : (y == 4) ? d4 : (y == 5) ? d5 : d6;
  const int n4 = (y < 3) ? (1 << 20) : (1 << 18);
  int i = blockIdx.x * 256 + threadIdx.x;
  if (i < n4) {
    floatx4 v = ((const floatx4*)s)[i];
    u16x4 o;
    o.x = f2bf(v.x); o.y = f2bf(v.y); o.z = f2bf(v.z); o.w = f2bf(v.w);
    ((u16x4*)d)[i] = o;
  }
}

// ---------------- batched 128x128 projection GEMM, C = A @ W^T + b -----------
// z=0: Q (scaled by 1/sqrt(64)*log2e), z=1: K  -> [N][H][2048][64]
// z=2: V -> transposed [N][H][64][2048]
__global__ __launch_bounds__(256) void gemm3(const u16* A0, const u16* A1, const u16* A2,
                                             const u16* W0, const u16* W1, const u16* W2,
                                             const float* b0, const float* b1, const float* b2,
                                             u16* o0, u16* o1, u16* o2) {
  __shared__ u16 lA[128 * 32];
  __shared__ u16 lB[128 * 32];
  const int z = blockIdx.z;
  const u16* A  = (z == 0) ? A0 : (z == 1) ? A1 : A2;
  const u16* Bw = (z == 0) ? W0 : (z == 1) ? W1 : W2;
  const float* bias = (z == 0) ? b0 : (z == 1) ? b1 : b2;
  u16* outp = (z == 0) ? o0 : (z == 1) ? o1 : o2;
  const float scl = (z == 0) ? (0.125f * 1.44269504089f) : 1.0f;

  const int tid = threadIdx.x;
  const int brow = blockIdx.y * 128, bcol = blockIdx.x * 128;
  const int lane = tid & 63, w = tid >> 6;
  const int wr = w >> 1, wc = w & 1;
  const int fr = lane & 15, fq = lane >> 4;
  f32x4 acc[4][4] = {};

  for (int k0 = 0; k0 < 1024; k0 += 32) {
    __syncthreads();
#pragma unroll
    for (int it = 0; it < 2; ++it) {
      int chunk = tid + it * 256;
      int row = chunk >> 2;
      int col = (chunk & 3) * 8;
      gload16(A  + (size_t)(brow + row) * 1024 + k0 + col, &lA[chunk * 8]);
      gload16(Bw + (size_t)(bcol + row) * 1024 + k0 + col, &lB[chunk * 8]);
    }
    __syncthreads();
    bf16x8 af[4], bfr[4];
#pragma unroll
    for (int m = 0; m < 4; ++m) af[m]  = *(const bf16x8*)&lA[(wr * 64 + m * 16 + fr) * 32 + fq * 8];
#pragma unroll
    for (int n = 0; n < 4; ++n) bfr[n] = *(const bf16x8*)&lB[(wc * 64 + n * 16 + fr) * 32 + fq * 8];
#pragma unroll
    for (int m = 0; m < 4; ++m)
#pragma unroll
      for (int n = 0; n < 4; ++n)
        acc[m][n] = __builtin_amdgcn_mfma_f32_16x16x32_bf16(af[m], bfr[n], acc[m][n], 0, 0, 0);
  }

#pragma unroll
  for (int m = 0; m < 4; ++m) {
#pragma unroll
    for (int n = 0; n < 4; ++n) {
      int colg = bcol + wc * 64 + n * 16 + fr;
      float bv = bias[colg];
#pragma unroll
      for (int j = 0; j < 4; ++j) {
        int rowg = brow + wr * 64 + m * 16 + fq * 4 + j;
        float v = (acc[m][n][j] + bv) * scl;
        int nb = rowg >> 11, l = rowg & 2047;
        int h = colg >> 6, dd = colg & 63;
        size_t idx = (z < 2) ? (((size_t)(nb * 16 + h) * 2048 + l) * 64 + dd)
                             : (((size_t)(nb * 16 + h) * 64 + dd) * 2048 + l);
        outp[idx] = f2bf(v);
      }
    }
  }
}

// ---------------- out-projection GEMM (f32 out) ------------------------------
__global__ __launch_bounds__(256) void gemm_o(const u16* __restrict__ A,
                                              const u16* __restrict__ Bw,
                                              const float* __restrict__ bias,
                                              float* __restrict__ outp) {
  __shared__ u16 lA[128 * 32];
  __shared__ u16 lB[128 * 32];
  const int tid = threadIdx.x;
  const int brow = blockIdx.y * 128, bcol = blockIdx.x * 128;
  const int lane = tid & 63, w = tid >> 6;
  const int wr = w >> 1, wc = w & 1;
  const int fr = lane & 15, fq = lane >> 4;
  f32x4 acc[4][4] = {};

  for (int k0 = 0; k0 < 1024; k0 += 32) {
    __syncthreads();
#pragma unroll
    for (int it = 0; it < 2; ++it) {
      int chunk = tid + it * 256;
      int row = chunk >> 2;
      int col = (chunk & 3) * 8;
      gload16(A  + (size_t)(brow + row) * 1024 + k0 + col, &lA[chunk * 8]);
      gload16(Bw + (size_t)(bcol + row) * 1024 + k0 + col, &lB[chunk * 8]);
    }
    __syncthreads();
    bf16x8 af[4], bfr[4];
#pragma unroll
    for (int m = 0; m < 4; ++m) af[m]  = *(const bf16x8*)&lA[(wr * 64 + m * 16 + fr) * 32 + fq * 8];
#pragma unroll
    for (int n = 0; n < 4; ++n) bfr[n] = *(const bf16x8*)&lB[(wc * 64 + n * 16 + fr) * 32 + fq * 8];
#pragma unroll
    for (int m = 0; m < 4; ++m)
#pragma unroll
      for (int n = 0; n < 4; ++n)
        acc[m][n] = __builtin_amdgcn_mfma_f32_16x16x32_bf16(af[m], bfr[n], acc[m][n], 0, 0, 0);
  }

#pragma unroll
  for (int m = 0; m < 4; ++m) {
#pragma unroll
    for (int n = 0; n < 4; ++n) {
      int colg = bcol + wc * 64 + n * 16 + fr;
      float bv = bias[colg];
#pragma unroll
      for (int j = 0; j < 4; ++j) {
        int rowg = brow + wr * 64 + m * 16 + fq * 4 + j;
        outp[(size_t)rowg * 1024 + colg] = acc[m][n][j] + bv;
      }
    }
  }
}

// ---------------- causal flash attention, uniform-chunk split-KV -------------
// Q,K: [NH=32][2048][64] bf16 (Q pre-scaled by 1/sqrt(64)*log2e); V^T: [NH][64][2048].
// Work unit = (head, q-tile t of 32 rows, KV-chunk p of up to 16 KV-tiles).
// Jobs per head: 160, laid out by chunk index p: c[] = {0, 64, 112, 144, 160};
// job j in [c[p], c[p+1]) -> t = 16p + (j - c[p]).  Each wave <= 16 iterations.
// Partial slot = global job id. acc bf16 [slot][32q][64d], m/l f32 [slot][32].
__global__ __launch_bounds__(256) void attn_part(const u16* __restrict__ Qp,
                                                 const u16* __restrict__ Kp,
                                                 const u16* __restrict__ Vt,
                                                 u16* __restrict__ accP,
                                                 float* __restrict__ mP,
                                                 float* __restrict__ lP) {
  const int lane = threadIdx.x & 63, w = threadIdx.x >> 6;
  const int wid = blockIdx.x * 4 + w;          // [0, 5120)
  const int nh = wid / 160;
  const int j = wid - nh * 160;
  int p, t;
  if (j < 64)       { p = 0; t = j; }
  else if (j < 112) { p = 1; t = 16 + (j - 64); }
  else if (j < 144) { p = 2; t = 32 + (j - 112); }
  else              { p = 3; t = 48 + (j - 144); }
  const int q0 = t * 32;
  const int col = lane & 31, hi = lane >> 5;
  const u16* Q = Qp + (size_t)nh * 2048 * 64;
  const u16* K = Kp + (size_t)nh * 2048 * 64;
  const u16* V = Vt + (size_t)nh * 64 * 2048;
  const int q = q0 + col;

  bf16x8 qf[4];
#pragma unroll
  for (int ks = 0; ks < 4; ++ks) qf[ks] = *(const bf16x8*)&Q[(size_t)q * 64 + ks * 16 + hi * 8];

  const int i0 = p * 16;
  const int i1 = min(i0 + 16, t + 1);

  f32x16 acc0 = {}, acc1 = {};   // out^T tiles: d in [0,32) and [32,64)
  float mrow = -1e30f, lrow = 0.f;

  for (int i = i0; i < i1; ++i) {
    const int s0 = i * 32;
    f32x16 sc = {};
    __builtin_amdgcn_s_setprio(1);
#pragma unroll
    for (int ks = 0; ks < 4; ++ks) {
      bf16x8 kf = *(const bf16x8*)&K[(size_t)(s0 + col) * 64 + ks * 16 + hi * 8];
      sc = __builtin_amdgcn_mfma_f32_32x32x16_bf16(kf, qf[ks], sc, 0, 0, 0);
    }
    __builtin_amdgcn_s_setprio(0);
    // lane holds S^T[s][q] for q=col: s-rows sr=(r&3)+8*(r>>2)+4*hi
    float pr[16];
    float pmax = -1e30f;
    const bool diag = (i == t);
#pragma unroll
    for (int r = 0; r < 16; ++r) {
      int sr = (r & 3) + 8 * (r >> 2) + 4 * hi;
      float v = sc[r];
      if (diag && sr > col) v = -1e30f;            // causal mask on diagonal tile
      pr[r] = v;
      pmax = fmaxf(pmax, v);
    }
    pmax = fmaxf(pmax, __shfl_xor(pmax, 32));
    // defer-max: rescale only when the running max grew by >8 (base-2 units)
    if (!__all(pmax <= mrow + 8.f)) {
      float mnew = fmaxf(mrow, pmax);
      float alpha = exp2f(mrow - mnew);
#pragma unroll
      for (int r = 0; r < 16; ++r) { acc0[r] *= alpha; acc1[r] *= alpha; }
      lrow *= alpha;
      mrow = mnew;
    }
    float ps = 0.f;
#pragma unroll
    for (int r = 0; r < 16; ++r) { float pv = exp2f(pr[r] - mrow); pr[r] = pv; ps += pv; }
    ps += __shfl_xor(ps, 32);
    lrow += ps;

    // Build PV B-operand (P^T as s x q), exchanging halves with lane^32
#pragma unroll
    for (int ks = 0; ks < 2; ++ks) {
      u32 A0 = cvtpk(pr[8 * ks + 0], pr[8 * ks + 1]);
      u32 A1 = cvtpk(pr[8 * ks + 2], pr[8 * ks + 3]);
      u32 B0 = cvtpk(pr[8 * ks + 4], pr[8 * ks + 5]);
      u32 B1 = cvtpk(pr[8 * ks + 6], pr[8 * ks + 7]);
      u32 t0 = __shfl_xor(hi ? A0 : B0, 32);
      u32 t1 = __shfl_xor(hi ? A1 : B1, 32);
      union { u32 u[4]; bf16x8 v; } pf;
      pf.u[0] = hi ? t0 : A0;
      pf.u[1] = hi ? t1 : A1;
      pf.u[2] = hi ? B0 : t0;
      pf.u[3] = hi ? B1 : t1;
      bf16x8 vf0 = *(const bf16x8*)&V[(size_t)(col) * 2048 + s0 + ks * 16 + hi * 8];
      bf16x8 vf1 = *(const bf16x8*)&V[(size_t)(32 + col) * 2048 + s0 + ks * 16 + hi * 8];
      __builtin_amdgcn_s_setprio(1);
      acc0 = __builtin_amdgcn_mfma_f32_32x32x16_bf16(vf0, pf.v, acc0, 0, 0, 0);
      acc1 = __builtin_amdgcn_mfma_f32_32x32x16_bf16(vf1, pf.v, acc1, 0, 0, 0);
      __builtin_amdgcn_s_setprio(0);
    }
  }

  // write unnormalized partial: acc [wid][q=col][d], m/l [wid][q]
  u16* base = accP + (size_t)wid * 2048 + col * 64;
#pragma unroll
  for (int rp = 0; rp < 8; ++rp) {
    int r = rp * 2;
    int d = (r & 3) + 8 * (r >> 2) + 4 * hi;
    *(u32*)&base[d]      = packbf(acc0[r], acc0[r + 1]);
    *(u32*)&base[32 + d] = packbf(acc1[r], acc1[r + 1]);
  }
  if (hi == 0) {
    mP[wid * 32 + col] = mrow;
    lP[wid * 32 + col] = lrow;
  }
}

// ---------------- combine up-to-4 partials per q-tile -> attn matrix ---------
// attn out: [N][2048][1024] bf16 (head-concat layout for the out projection)
__global__ void combineN(const u16* __restrict__ accP, const float* __restrict__ mP,
                         const float* __restrict__ lP, u16* __restrict__ at) {
  const int t = blockIdx.x;              // [0,64)
  const int nh = blockIdx.y;             // [0,32)
  const int q = threadIdx.x >> 3;        // [0,32)
  const int d0 = (threadIdx.x & 7) * 8;  // [0,64) step 8
  const int np = (t >> 4) + 1;           // parts: 1..4
  // slot(p) = nh*160 + c[p] + (t - 16p), c = {0,64,112,144}
  const int s0 = nh * 160 + t;
  const int s1 = nh * 160 + 64 + (t - 16);
  const int s2 = nh * 160 + 112 + (t - 32);
  const int s3 = nh * 160 + 144 + (t - 48);

  float m = mP[s0 * 32 + q];
  if (np > 1) m = fmaxf(m, mP[s1 * 32 + q]);
  if (np > 2) m = fmaxf(m, mP[s2 * 32 + q]);
  if (np > 3) m = fmaxf(m, mP[s3 * 32 + q]);
  float w0 = exp2f(mP[s0 * 32 + q] - m);
  float w1 = (np > 1) ? exp2f(mP[s1 * 32 + q] - m) : 0.f;
  float w2 = (np > 2) ? exp2f(mP[s2 * 32 + q] - m) : 0.f;
  float w3 = (np > 3) ? exp2f(mP[s3 * 32 + q] - m) : 0.f;
  float l = lP[s0 * 32 + q] * w0;
  if (np > 1) l += lP[s1 * 32 + q] * w1;
  if (np > 2) l += lP[s2 * 32 + q] * w2;
  if (np > 3) l += lP[s3 * 32 + q] * w3;
  const float inv = 1.f / l;
  w0 *= inv; w1 *= inv; w2 *= inv; w3 *= inv;

  float o[8] = {};
  {
    const bf16x8 a = *(const bf16x8*)&accP[(size_t)s0 * 2048 + q * 64 + d0];
#pragma unroll
    for (int k = 0; k < 8; ++k) o[k] += bf2f((u16)a[k]) * w0;
  }
  if (np > 1) {
    const bf16x8 a = *(const bf16x8*)&accP[(size_t)s1 * 2048 + q * 64 + d0];
#pragma unroll
    for (int k = 0; k < 8; ++k) o[k] += bf2f((u16)a[k]) * w1;
  }
  if (np > 2) {
    const bf16x8 a = *(const bf16x8*)&accP[(size_t)s2 * 2048 + q * 64 + d0];
#pragma unroll
    for (int k = 0; k < 8; ++k) o[k] += bf2f((u16)a[k]) * w2;
  }
  if (np > 3) {
    const bf16x8 a = *(const bf16x8*)&accP[(size_t)s3 * 2048 + q * 64 + d0];
#pragma unroll
    for (int k = 0; k < 8; ++k) o[k] += bf2f((u16)a[k]) * w3;
  }

  const int nb = nh >> 4, h = nh & 15;
  u16* op = &at[((size_t)(nb * 2048 + t * 32 + q)) * 1024 + h * 64 + d0];
#pragma unroll
  for (int jj = 0; jj < 4; ++jj)
    *(u32*)&op[2 * jj] = packbf(o[2 * jj], o[2 * jj + 1]);
}

// -----------------------------------------------------------------------------
extern "C" void kernel_launch(void* const* d_in, const int* in_sizes, int n_in,
                              void* d_out, int out_size, void* d_ws, size_t ws_size,
                              hipStream_t stream) {
  const float* queries = (const float*)d_in[0];
  const float* keys    = (const float*)d_in[1];
  const float* values  = (const float*)d_in[2];
  const float* Wq = (const float*)d_in[3]; const float* bq = (const float*)d_in[4];
  const float* Wk = (const float*)d_in[5]; const float* bk = (const float*)d_in[6];
  const float* Wv = (const float*)d_in[7]; const float* bv = (const float*)d_in[8];
  const float* Wo = (const float*)d_in[9]; const float* bo = (const float*)d_in[10];
  float* out = (float*)d_out;
  char* ws = (char*)d_ws;

  const size_t MB = 1u << 20;
  u16* xq  = (u16*)(ws + 0 * MB);    // 8 MB (reused as attn output `at`)
  u16* xk  = (u16*)(ws + 8 * MB);
  u16* xv  = (u16*)(ws + 16 * MB);
  u16* wqb = (u16*)(ws + 24 * MB);
  u16* wkb = (u16*)(ws + 26 * MB);
  u16* wvb = (u16*)(ws + 28 * MB);
  u16* wob = (u16*)(ws + 30 * MB);   // LIVE until gemm_o
  u16* qp  = (u16*)(ws + 32 * MB);
  u16* kp  = (u16*)(ws + 40 * MB);
  u16* vt  = (u16*)(ws + 48 * MB);
  u16* at  = xq;                            // attn out reuses xq
  // split-KV partials: 5120 slots x 4KB = 20 MB at [8,28); m/l 1.25 MB at [28,30)
  u16*   accP = (u16*)(ws + 8 * MB);
  float* mPp  = (float*)(ws + 28 * MB);
  float* lPp  = (float*)(ws + 28 * MB + 5120 * 32 * sizeof(float));

  // fp32 -> bf16 (all tensors, one launch)
  cvt7<<<dim3(4096, 7), 256, 0, stream>>>(queries, keys, values, Wq, Wk, Wv, Wo,
                                          xq, xk, xv, wqb, wkb, wvb, wob);
  // Q/K/V projections, one batched launch (768 blocks = 3/CU)
  gemm3<<<dim3(8, 32, 3), 256, 0, stream>>>(xq, xk, xv, wqb, wkb, wvb,
                                            bq, bk, bv, qp, kp, vt);
  // attention partials: 5120 uniform jobs (1280 blocks) + combine
  attn_part<<<1280, 256, 0, stream>>>(qp, kp, vt, accP, mPp, lPp);
  combineN<<<dim3(64, 32), 256, 0, stream>>>(accP, mPp, lPp, at);
  // output projection
  gemm_o<<<dim3(8, 32), 256, 0, stream>>>(at, wob, bo, out);
}

// Round 5
// 249.669 us; speedup vs baseline: 1.3312x; 1.1380x over previous
//
#include <hip/hip_runtime.h>

typedef unsigned short u16;
typedef unsigned int u32;
typedef __attribute__((ext_vector_type(8))) short bf16x8;   // 8 bf16 = 4 VGPRs
typedef __attribute__((ext_vector_type(4))) float f32x4;
typedef __attribute__((ext_vector_type(16))) float f32x16;
typedef __attribute__((ext_vector_type(4))) float floatx4;
typedef __attribute__((ext_vector_type(4))) u16 u16x4;

__device__ __forceinline__ u16 f2bf(float x) {
  union { float f; u32 u; } c; c.f = x;
  return (u16)((c.u + 0x7fffu + ((c.u >> 16) & 1u)) >> 16);  // RNE
}
__device__ __forceinline__ u32 packbf(float a, float b) {
  return (u32)f2bf(a) | ((u32)f2bf(b) << 16);
}
__device__ __forceinline__ u32 cvtpk(float lo, float hi) {
  u32 r;
  asm("v_cvt_pk_bf16_f32 %0, %1, %2" : "=v"(r) : "v"(lo), "v"(hi));
  return r;
}
__device__ __forceinline__ float bf2f(u16 v) {
  union { u32 u; float f; } c; c.u = (u32)v << 16; return c.f;
}

__device__ __forceinline__ void gload16(const u16* g, u16* l) {
  auto gp = (const __attribute__((address_space(1))) unsigned int*)g;
  auto lp = (__attribute__((address_space(3))) unsigned int*)l;
  __builtin_amdgcn_global_load_lds(gp, lp, 16, 0, 0);
}

// ---------------- fp32 -> bf16: all 7 tensors in one launch ------------------
__global__ void cvt7(const float* s0, const float* s1, const float* s2,
                     const float* s3, const float* s4, const float* s5, const float* s6,
                     u16* d0, u16* d1, u16* d2, u16* d3, u16* d4, u16* d5, u16* d6) {
  const int y = blockIdx.y;
  const float* s = (y == 0) ? s0 : (y == 1) ? s1 : (y == 2) ? s2 : (y == 3) ? s3
                  : (y == 4) ? s4 : (y == 5) ? s5 : s6;
  u16* d = (y == 0) ? d0 : (y == 1) ? d1 : (y == 2) ? d2 : (y == 3) ? d3
          : (y == 4) ? d4 : (y == 5) ? d5 : d6;
  const int n4 = (y < 3) ? (1 << 20) : (1 << 18);
  int i = blockIdx.x * 256 + threadIdx.x;
  if (i < n4) {
    floatx4 v = ((const floatx4*)s)[i];
    u16x4 o;
    o.x = f2bf(v.x); o.y = f2bf(v.y); o.z = f2bf(v.z); o.w = f2bf(v.w);
    ((u16x4*)d)[i] = o;
  }
}

// ---------------- batched 128x128 projection GEMM, C = A @ W^T + b -----------
// z=0: Q (scaled by 1/sqrt(64)*log2e), z=1: K  -> [N][H][2048][64]
// z=2: V -> transposed [N][H][64][2048]
__global__ __launch_bounds__(256) void gemm3(const u16* A0, const u16* A1, const u16* A2,
                                             const u16* W0, const u16* W1, const u16* W2,
                                             const float* b0, const float* b1, const float* b2,
                                             u16* o0, u16* o1, u16* o2) {
  __shared__ u16 lA[128 * 32];
  __shared__ u16 lB[128 * 32];
  const int z = blockIdx.z;
  const u16* A  = (z == 0) ? A0 : (z == 1) ? A1 : A2;
  const u16* Bw = (z == 0) ? W0 : (z == 1) ? W1 : W2;
  const float* bias = (z == 0) ? b0 : (z == 1) ? b1 : b2;
  u16* outp = (z == 0) ? o0 : (z == 1) ? o1 : o2;
  const float scl = (z == 0) ? (0.125f * 1.44269504089f) : 1.0f;

  const int tid = threadIdx.x;
  const int brow = blockIdx.y * 128, bcol = blockIdx.x * 128;
  const int lane = tid & 63, w = tid >> 6;
  const int wr = w >> 1, wc = w & 1;
  const int fr = lane & 15, fq = lane >> 4;
  f32x4 acc[4][4] = {};

  for (int k0 = 0; k0 < 1024; k0 += 32) {
    __syncthreads();
#pragma unroll
    for (int it = 0; it < 2; ++it) {
      int chunk = tid + it * 256;
      int row = chunk >> 2;
      int col = (chunk & 3) * 8;
      gload16(A  + (size_t)(brow + row) * 1024 + k0 + col, &lA[chunk * 8]);
      gload16(Bw + (size_t)(bcol + row) * 1024 + k0 + col, &lB[chunk * 8]);
    }
    __syncthreads();
    bf16x8 af[4], bfr[4];
#pragma unroll
    for (int m = 0; m < 4; ++m) af[m]  = *(const bf16x8*)&lA[(wr * 64 + m * 16 + fr) * 32 + fq * 8];
#pragma unroll
    for (int n = 0; n < 4; ++n) bfr[n] = *(const bf16x8*)&lB[(wc * 64 + n * 16 + fr) * 32 + fq * 8];
#pragma unroll
    for (int m = 0; m < 4; ++m)
#pragma unroll
      for (int n = 0; n < 4; ++n)
        acc[m][n] = __builtin_amdgcn_mfma_f32_16x16x32_bf16(af[m], bfr[n], acc[m][n], 0, 0, 0);
  }

#pragma unroll
  for (int m = 0; m < 4; ++m) {
#pragma unroll
    for (int n = 0; n < 4; ++n) {
      int colg = bcol + wc * 64 + n * 16 + fr;
      float bv = bias[colg];
#pragma unroll
      for (int j = 0; j < 4; ++j) {
        int rowg = brow + wr * 64 + m * 16 + fq * 4 + j;
        float v = (acc[m][n][j] + bv) * scl;
        int nb = rowg >> 11, l = rowg & 2047;
        int h = colg >> 6, dd = colg & 63;
        size_t idx = (z < 2) ? (((size_t)(nb * 16 + h) * 2048 + l) * 64 + dd)
                             : (((size_t)(nb * 16 + h) * 64 + dd) * 2048 + l);
        outp[idx] = f2bf(v);
      }
    }
  }
}

// ---------------- out-projection GEMM (f32 out) ------------------------------
__global__ __launch_bounds__(256) void gemm_o(const u16* __restrict__ A,
                                              const u16* __restrict__ Bw,
                                              const float* __restrict__ bias,
                                              float* __restrict__ outp) {
  __shared__ u16 lA[128 * 32];
  __shared__ u16 lB[128 * 32];
  const int tid = threadIdx.x;
  const int brow = blockIdx.y * 128, bcol = blockIdx.x * 128;
  const int lane = tid & 63, w = tid >> 6;
  const int wr = w >> 1, wc = w & 1;
  const int fr = lane & 15, fq = lane >> 4;
  f32x4 acc[4][4] = {};

  for (int k0 = 0; k0 < 1024; k0 += 32) {
    __syncthreads();
#pragma unroll
    for (int it = 0; it < 2; ++it) {
      int chunk = tid + it * 256;
      int row = chunk >> 2;
      int col = (chunk & 3) * 8;
      gload16(A  + (size_t)(brow + row) * 1024 + k0 + col, &lA[chunk * 8]);
      gload16(Bw + (size_t)(bcol + row) * 1024 + k0 + col, &lB[chunk * 8]);
    }
    __syncthreads();
    bf16x8 af[4], bfr[4];
#pragma unroll
    for (int m = 0; m < 4; ++m) af[m]  = *(const bf16x8*)&lA[(wr * 64 + m * 16 + fr) * 32 + fq * 8];
#pragma unroll
    for (int n = 0; n < 4; ++n) bfr[n] = *(const bf16x8*)&lB[(wc * 64 + n * 16 + fr) * 32 + fq * 8];
#pragma unroll
    for (int m = 0; m < 4; ++m)
#pragma unroll
      for (int n = 0; n < 4; ++n)
        acc[m][n] = __builtin_amdgcn_mfma_f32_16x16x32_bf16(af[m], bfr[n], acc[m][n], 0, 0, 0);
  }

#pragma unroll
  for (int m = 0; m < 4; ++m) {
#pragma unroll
    for (int n = 0; n < 4; ++n) {
      int colg = bcol + wc * 64 + n * 16 + fr;
      float bv = bias[colg];
#pragma unroll
      for (int j = 0; j < 4; ++j) {
        int rowg = brow + wr * 64 + m * 16 + fq * 4 + j;
        outp[(size_t)rowg * 1024 + colg] = acc[m][n][j] + bv;
      }
    }
  }
}

// ---------------- causal flash attention: LDS-shared K/V, 4 waves/block ------
// Q,K: [NH=32][2048][64] bf16 (Q pre-scaled); V^T: [NH][64][2048] bf16.
// Block = one head, 128 q-rows (4 waves x 32), KV chunk of <=16 tiles (512 pos).
// Jobs/head = 40: c[] = {0,16,28,36,40}, base_t = {0,4,8,12}.
// K/V tiles double-buffered in LDS via global_load_lds; XOR-swizzled rows
// (linear LDS dest + inverse-swizzled global source, rule #21).
// Partials: acc bf16 [job][128q][64d], m/l f32 [job][128].
__global__ __launch_bounds__(256) void attn_part(const u16* __restrict__ Qp,
                                                 const u16* __restrict__ Kp,
                                                 const u16* __restrict__ Vt,
                                                 u16* __restrict__ accP,
                                                 float* __restrict__ mP,
                                                 float* __restrict__ lP) {
  __shared__ u16 lK[2][2048];   // 2 x 32 rows x 128 B (swizzled)
  __shared__ u16 lV[2][2048];   // 2 x 32 lrows x 128 B; lrow l = V^T rows {l, l+32}
  const int tid = threadIdx.x;
  const int lane = tid & 63, w = tid >> 6;
  const int bid = blockIdx.x;          // [0,1280)
  const int nh = bid / 40;
  const int j = bid - nh * 40;
  int p, t;
  if (j < 16)      { p = 0; t = j; }
  else if (j < 28) { p = 1; t = 4 + (j - 16); }
  else if (j < 36) { p = 2; t = 8 + (j - 28); }
  else             { p = 3; t = 12 + (j - 36); }
  const int i0 = p * 16;
  const int i1 = min(i0 + 16, (t + 1) * 4);
  const int col = lane & 31, hi = lane >> 5;
  const u16* Q = Qp + (size_t)nh * 2048 * 64;
  const u16* K = Kp + (size_t)nh * 2048 * 64;
  const u16* V = Vt + (size_t)nh * 64 * 2048;
  const int q = t * 128 + w * 32 + col;   // this wave-lane's q row
  const int swz = (col & 7) << 4;         // read-side swizzle (bytes)

  // staging geometry: thread stages LDS bytes [tid*16, tid*16+16)
  const int kr  = tid >> 3;                                   // K row / V lrow
  const int kin = ((tid & 7) * 16) ^ ((kr & 7) << 4);         // unswizzled inner byte
  const int vd  = kr + ((kin >> 6) << 5);                     // V^T d-row
  const int vs  = (kin & 63) >> 1;                            // s offset in tile

  bf16x8 qf[4];
#pragma unroll
  for (int ks = 0; ks < 4; ++ks) qf[ks] = *(const bf16x8*)&Q[(size_t)q * 64 + ks * 16 + hi * 8];

  f32x16 acc0 = {}, acc1 = {};   // out^T tiles: d in [0,32) and [32,64)
  float mrow = -1e30f, lrow = 0.f;

  // prologue stage
  {
    const int s0 = i0 * 32;
    gload16(K + (size_t)(s0 + kr) * 64 + (kin >> 1), &lK[0][tid * 8]);
    gload16(V + (size_t)vd * 2048 + (s0 + vs),       &lV[0][tid * 8]);
  }
  __syncthreads();

  int cur = 0;
  for (int i = i0; i < i1; ++i) {
    if (i + 1 < i1) {                     // prefetch next tile into other buffer
      const int s0n = (i + 1) * 32;
      gload16(K + (size_t)(s0n + kr) * 64 + (kin >> 1), &lK[cur ^ 1][tid * 8]);
      gload16(V + (size_t)vd * 2048 + (s0n + vs),       &lV[cur ^ 1][tid * 8]);
    }
    const int s0 = i * 32;
    f32x16 sc = {};
    __builtin_amdgcn_s_setprio(1);
#pragma unroll
    for (int ks = 0; ks < 4; ++ks) {
      bf16x8 kf = *(const bf16x8*)&lK[cur][col * 64 + (((ks * 32 + hi * 16) ^ swz) >> 1)];
      sc = __builtin_amdgcn_mfma_f32_32x32x16_bf16(kf, qf[ks], sc, 0, 0, 0);
    }
    __builtin_amdgcn_s_setprio(0);
    // lane holds S^T[s][q] for q-row = q: s index sr=(r&3)+8*(r>>2)+4*hi
    float pr[16];
    float pmax = -1e30f;
#pragma unroll
    for (int r = 0; r < 16; ++r) {
      int sr = (r & 3) + 8 * (r >> 2) + 4 * hi;
      float v = (s0 + sr > q) ? -1e30f : sc[r];   // causal mask
      pr[r] = v;
      pmax = fmaxf(pmax, v);
    }
    pmax = fmaxf(pmax, __shfl_xor(pmax, 32));
    // defer-max: rescale only when the running max grew by >8 (base-2 units)
    if (!__all(pmax <= mrow + 8.f)) {
      float mnew = fmaxf(mrow, pmax);
      float alpha = exp2f(mrow - mnew);
#pragma unroll
      for (int r = 0; r < 16; ++r) { acc0[r] *= alpha; acc1[r] *= alpha; }
      lrow *= alpha;
      mrow = mnew;
    }
    float ps = 0.f;
#pragma unroll
    for (int r = 0; r < 16; ++r) { float pv = exp2f(pr[r] - mrow); pr[r] = pv; ps += pv; }
    ps += __shfl_xor(ps, 32);
    lrow += ps;

    // Build PV B-operand (P^T as s x q), exchanging halves with lane^32
#pragma unroll
    for (int ks = 0; ks < 2; ++ks) {
      u32 A0 = cvtpk(pr[8 * ks + 0], pr[8 * ks + 1]);
      u32 A1 = cvtpk(pr[8 * ks + 2], pr[8 * ks + 3]);
      u32 B0 = cvtpk(pr[8 * ks + 4], pr[8 * ks + 5]);
      u32 B1 = cvtpk(pr[8 * ks + 6], pr[8 * ks + 7]);
      u32 t0 = __shfl_xor(hi ? A0 : B0, 32);
      u32 t1 = __shfl_xor(hi ? A1 : B1, 32);
      union { u32 u[4]; bf16x8 v; } pf;
      pf.u[0] = hi ? t0 : A0;
      pf.u[1] = hi ? t1 : A1;
      pf.u[2] = hi ? B0 : t0;
      pf.u[3] = hi ? B1 : t1;
      bf16x8 vf0 = *(const bf16x8*)&lV[cur][col * 64 + (((ks * 32 + hi * 16) ^ swz) >> 1)];
      bf16x8 vf1 = *(const bf16x8*)&lV[cur][col * 64 + (((64 + ks * 32 + hi * 16) ^ swz) >> 1)];
      __builtin_amdgcn_s_setprio(1);
      acc0 = __builtin_amdgcn_mfma_f32_32x32x16_bf16(vf0, pf.v, acc0, 0, 0, 0);
      acc1 = __builtin_amdgcn_mfma_f32_32x32x16_bf16(vf1, pf.v, acc1, 0, 0, 0);
      __builtin_amdgcn_s_setprio(0);
    }
    __syncthreads();   // drains prefetch (vmcnt) + all LDS reads of buf[cur]
    cur ^= 1;
  }

  // write unnormalized partial: acc [bid][q_local][d], m/l [bid][q_local]
  const int ql = w * 32 + col;
  u16* base = accP + (size_t)bid * 8192 + ql * 64;
#pragma unroll
  for (int rp = 0; rp < 8; ++rp) {
    int r = rp * 2;
    int d = (r & 3) + 8 * (r >> 2) + 4 * hi;
    *(u32*)&base[d]      = packbf(acc0[r], acc0[r + 1]);
    *(u32*)&base[32 + d] = packbf(acc1[r], acc1[r + 1]);
  }
  if (hi == 0) {
    mP[bid * 128 + ql] = mrow;
    lP[bid * 128 + ql] = lrow;
  }
}

// ---------------- combine up-to-4 partials per 128-row q-tile ----------------
// attn out: [N][2048][1024] bf16 (head-concat layout for the out projection)
__global__ void combineN(const u16* __restrict__ accP, const float* __restrict__ mP,
                         const float* __restrict__ lP, u16* __restrict__ at) {
  const int t = blockIdx.x >> 2;             // [0,16) q-tile of 128 rows
  const int seg = blockIdx.x & 3;            // 32-row segment
  const int nh = blockIdx.y;                 // [0,32)
  const int ql = seg * 32 + (threadIdx.x >> 3);   // [0,128)
  const int d0 = (threadIdx.x & 7) * 8;      // [0,64) step 8
  const int np = (t >> 2) + 1;               // parts: 1..4
  // slot(p) = nh*40 + c[p] + (t - 4p), c = {0,16,28,36}
  const int s0 = nh * 40 + t;
  const int s1 = nh * 40 + 16 + (t - 4);
  const int s2 = nh * 40 + 28 + (t - 8);
  const int s3 = nh * 40 + 36 + (t - 12);

  float m = mP[s0 * 128 + ql];
  if (np > 1) m = fmaxf(m, mP[s1 * 128 + ql]);
  if (np > 2) m = fmaxf(m, mP[s2 * 128 + ql]);
  if (np > 3) m = fmaxf(m, mP[s3 * 128 + ql]);
  float w0 = exp2f(mP[s0 * 128 + ql] - m);
  float w1 = (np > 1) ? exp2f(mP[s1 * 128 + ql] - m) : 0.f;
  float w2 = (np > 2) ? exp2f(mP[s2 * 128 + ql] - m) : 0.f;
  float w3 = (np > 3) ? exp2f(mP[s3 * 128 + ql] - m) : 0.f;
  float l = lP[s0 * 128 + ql] * w0;
  if (np > 1) l += lP[s1 * 128 + ql] * w1;
  if (np > 2) l += lP[s2 * 128 + ql] * w2;
  if (np > 3) l += lP[s3 * 128 + ql] * w3;
  const float inv = 1.f / l;
  w0 *= inv; w1 *= inv; w2 *= inv; w3 *= inv;

  float o[8] = {};
  {
    const bf16x8 a = *(const bf16x8*)&accP[(size_t)s0 * 8192 + ql * 64 + d0];
#pragma unroll
    for (int k = 0; k < 8; ++k) o[k] += bf2f((u16)a[k]) * w0;
  }
  if (np > 1) {
    const bf16x8 a = *(const bf16x8*)&accP[(size_t)s1 * 8192 + ql * 64 + d0];
#pragma unroll
    for (int k = 0; k < 8; ++k) o[k] += bf2f((u16)a[k]) * w1;
  }
  if (np > 2) {
    const bf16x8 a = *(const bf16x8*)&accP[(size_t)s2 * 8192 + ql * 64 + d0];
#pragma unroll
    for (int k = 0; k < 8; ++k) o[k] += bf2f((u16)a[k]) * w2;
  }
  if (np > 3) {
    const bf16x8 a = *(const bf16x8*)&accP[(size_t)s3 * 8192 + ql * 64 + d0];
#pragma unroll
    for (int k = 0; k < 8; ++k) o[k] += bf2f((u16)a[k]) * w3;
  }

  const int nb = nh >> 4, h = nh & 15;
  u16* op = &at[((size_t)(nb * 2048 + t * 128 + ql)) * 1024 + h * 64 + d0];
#pragma unroll
  for (int jj = 0; jj < 4; ++jj)
    *(u32*)&op[2 * jj] = packbf(o[2 * jj], o[2 * jj + 1]);
}

// -----------------------------------------------------------------------------
extern "C" void kernel_launch(void* const* d_in, const int* in_sizes, int n_in,
                              void* d_out, int out_size, void* d_ws, size_t ws_size,
                              hipStream_t stream) {
  const float* queries = (const float*)d_in[0];
  const float* keys    = (const float*)d_in[1];
  const float* values  = (const float*)d_in[2];
  const float* Wq = (const float*)d_in[3]; const float* bq = (const float*)d_in[4];
  const float* Wk = (const float*)d_in[5]; const float* bk = (const float*)d_in[6];
  const float* Wv = (const float*)d_in[7]; const float* bv = (const float*)d_in[8];
  const float* Wo = (const float*)d_in[9]; const float* bo = (const float*)d_in[10];
  float* out = (float*)d_out;
  char* ws = (char*)d_ws;

  const size_t MB = 1u << 20;
  u16* xq  = (u16*)(ws + 0 * MB);    // 8 MB (reused as attn output `at`)
  u16* xk  = (u16*)(ws + 8 * MB);
  u16* xv  = (u16*)(ws + 16 * MB);
  u16* wqb = (u16*)(ws + 24 * MB);
  u16* wkb = (u16*)(ws + 26 * MB);
  u16* wvb = (u16*)(ws + 28 * MB);
  u16* wob = (u16*)(ws + 30 * MB);   // LIVE until gemm_o
  u16* qp  = (u16*)(ws + 32 * MB);
  u16* kp  = (u16*)(ws + 40 * MB);
  u16* vt  = (u16*)(ws + 48 * MB);
  u16* at  = xq;                            // attn out reuses xq
  // split-KV partials: 1280 slots x 16 KB = 20 MB at [8,28); m/l 640 KB each
  u16*   accP = (u16*)(ws + 8 * MB);
  float* mPp  = (float*)(ws + 28 * MB);
  float* lPp  = (float*)(ws + 28 * MB + 1280 * 128 * sizeof(float));

  // fp32 -> bf16 (all tensors, one launch)
  cvt7<<<dim3(4096, 7), 256, 0, stream>>>(queries, keys, values, Wq, Wk, Wv, Wo,
                                          xq, xk, xv, wqb, wkb, wvb, wob);
  // Q/K/V projections, one batched launch (768 blocks = 3/CU)
  gemm3<<<dim3(8, 32, 3), 256, 0, stream>>>(xq, xk, xv, wqb, wkb, wvb,
                                            bq, bk, bv, qp, kp, vt);
  // attention partials: 1280 blocks (4 waves, LDS-shared K/V) + combine
  attn_part<<<1280, 256, 0, stream>>>(qp, kp, vt, accP, mPp, lPp);
  combineN<<<dim3(64, 32), 256, 0, stream>>>(accP, mPp, lPp, at);
  // output projection
  gemm_o<<<dim3(8, 32), 256, 0, stream>>>(at, wob, bo, out);
}

// Round 8
// 245.651 us; speedup vs baseline: 1.3530x; 1.0164x over previous
//
#include <hip/hip_runtime.h>

typedef unsigned short u16;
typedef unsigned int u32;
typedef __attribute__((ext_vector_type(8))) short bf16x8;   // 8 bf16 = 4 VGPRs
typedef __attribute__((ext_vector_type(4))) float f32x4;
typedef __attribute__((ext_vector_type(16))) float f32x16;
typedef __attribute__((ext_vector_type(4))) float floatx4;
typedef __attribute__((ext_vector_type(4))) u16 u16x4;

__device__ __forceinline__ u16 f2bf(float x) {
  union { float f; u32 u; } c; c.f = x;
  return (u16)((c.u + 0x7fffu + ((c.u >> 16) & 1u)) >> 16);  // RNE
}
__device__ __forceinline__ u32 packbf(float a, float b) {
  return (u32)f2bf(a) | ((u32)f2bf(b) << 16);
}
__device__ __forceinline__ u32 cvtpk(float lo, float hi) {
  u32 r;
  asm("v_cvt_pk_bf16_f32 %0, %1, %2" : "=v"(r) : "v"(lo), "v"(hi));
  return r;
}
__device__ __forceinline__ float bf2f(u16 v) {
  union { u32 u; float f; } c; c.u = (u32)v << 16; return c.f;
}

__device__ __forceinline__ void gload16(const u16* g, u16* l) {
  auto gp = (const __attribute__((address_space(1))) unsigned int*)g;
  auto lp = (__attribute__((address_space(3))) unsigned int*)l;
  __builtin_amdgcn_global_load_lds(gp, lp, 16, 0, 0);
}

#define WAIT_VM4() asm volatile("s_waitcnt vmcnt(4)" ::: "memory")
#define WAIT_VM0() asm volatile("s_waitcnt vmcnt(0)" ::: "memory")
#define WAIT_LGKM0() asm volatile("s_waitcnt lgkmcnt(0)" ::: "memory")

// ---------------- fp32 -> bf16: all 7 tensors in one launch ------------------
__global__ void cvt7(const float* s0, const float* s1, const float* s2,
                     const float* s3, const float* s4, const float* s5, const float* s6,
                     u16* d0, u16* d1, u16* d2, u16* d3, u16* d4, u16* d5, u16* d6) {
  const int y = blockIdx.y;
  const float* s = (y == 0) ? s0 : (y == 1) ? s1 : (y == 2) ? s2 : (y == 3) ? s3
                  : (y == 4) ? s4 : (y == 5) ? s5 : s6;
  u16* d = (y == 0) ? d0 : (y == 1) ? d1 : (y == 2) ? d2 : (y == 3) ? d3
          : (y == 4) ? d4 : (y == 5) ? d5 : d6;
  const int n4 = (y < 3) ? (1 << 20) : (1 << 18);
  int i = blockIdx.x * 256 + threadIdx.x;
  if (i < n4) {
    floatx4 v = ((const floatx4*)s)[i];
    u16x4 o;
    o.x = f2bf(v.x); o.y = f2bf(v.y); o.z = f2bf(v.z); o.w = f2bf(v.w);
    ((u16x4*)d)[i] = o;
  }
}

// ---------------- batched 128x128 projection GEMM, C = A @ W^T + b -----------
// Double-buffered LDS, counted vmcnt, raw barriers (T3-min + T4).
// z=0: Q (scaled by 1/sqrt(64)*log2e), z=1: K  -> [N][H][2048][64]
// z=2: V -> transposed [N][H][64][2048]
__global__ __launch_bounds__(256) void gemm3(const u16* A0, const u16* A1, const u16* A2,
                                             const u16* W0, const u16* W1, const u16* W2,
                                             const float* b0, const float* b1, const float* b2,
                                             u16* o0, u16* o1, u16* o2) {
  __shared__ u16 lA[2][128 * 32];
  __shared__ u16 lB[2][128 * 32];
  const int z = blockIdx.z;
  const u16* A  = (z == 0) ? A0 : (z == 1) ? A1 : A2;
  const u16* Bw = (z == 0) ? W0 : (z == 1) ? W1 : W2;
  const float* bias = (z == 0) ? b0 : (z == 1) ? b1 : b2;
  u16* outp = (z == 0) ? o0 : (z == 1) ? o1 : o2;
  const float scl = (z == 0) ? (0.125f * 1.44269504089f) : 1.0f;

  const int tid = threadIdx.x;
  const int brow = blockIdx.y * 128, bcol = blockIdx.x * 128;
  const int lane = tid & 63, w = tid >> 6;
  const int wr = w >> 1, wc = w & 1;
  const int fr = lane & 15, fq = lane >> 4;
  f32x4 acc[4][4] = {};

  auto stageg = [&](int ks, int bb) {
#pragma unroll
    for (int it = 0; it < 2; ++it) {
      int chunk = tid + it * 256;
      int row = chunk >> 2;
      int colb = (chunk & 3) * 8;
      gload16(A  + (size_t)(brow + row) * 1024 + ks * 32 + colb, &lA[bb][chunk * 8]);
      gload16(Bw + (size_t)(bcol + row) * 1024 + ks * 32 + colb, &lB[bb][chunk * 8]);
    }
  };

  float bvr[4];
#pragma unroll
  for (int n = 0; n < 4; ++n) bvr[n] = bias[bcol + wc * 64 + n * 16 + fr];

  stageg(0, 0);
  WAIT_VM0();
  __builtin_amdgcn_s_barrier();

  for (int kk = 0; kk < 32; ++kk) {
    const int cur = kk & 1;
    if (kk + 1 < 32) { stageg(kk + 1, cur ^ 1); WAIT_VM4(); }
    else             { WAIT_VM0(); }
    __builtin_amdgcn_s_barrier();
    __builtin_amdgcn_sched_barrier(0);

    bf16x8 af[4], bfr[4];
#pragma unroll
    for (int m = 0; m < 4; ++m) af[m]  = *(const bf16x8*)&lA[cur][(wr * 64 + m * 16 + fr) * 32 + fq * 8];
#pragma unroll
    for (int n = 0; n < 4; ++n) bfr[n] = *(const bf16x8*)&lB[cur][(wc * 64 + n * 16 + fr) * 32 + fq * 8];
    __builtin_amdgcn_s_setprio(1);
#pragma unroll
    for (int m = 0; m < 4; ++m)
#pragma unroll
      for (int n = 0; n < 4; ++n)
        acc[m][n] = __builtin_amdgcn_mfma_f32_16x16x32_bf16(af[m], bfr[n], acc[m][n], 0, 0, 0);
    __builtin_amdgcn_s_setprio(0);

    WAIT_LGKM0();
    __builtin_amdgcn_s_barrier();
  }

#pragma unroll
  for (int m = 0; m < 4; ++m) {
#pragma unroll
    for (int n = 0; n < 4; ++n) {
      int colg = bcol + wc * 64 + n * 16 + fr;
#pragma unroll
      for (int j = 0; j < 4; ++j) {
        int rowg = brow + wr * 64 + m * 16 + fq * 4 + j;
        float v = (acc[m][n][j] + bvr[n]) * scl;
        int nb = rowg >> 11, l = rowg & 2047;
        int h = colg >> 6, dd = colg & 63;
        size_t idx = (z < 2) ? (((size_t)(nb * 16 + h) * 2048 + l) * 64 + dd)
                             : (((size_t)(nb * 16 + h) * 64 + dd) * 2048 + l);
        outp[idx] = f2bf(v);
      }
    }
  }
}

// ---------------- out-projection GEMM (f32 out), same dbuf structure ---------
__global__ __launch_bounds__(256) void gemm_o(const u16* __restrict__ A,
                                              const u16* __restrict__ Bw,
                                              const float* __restrict__ bias,
                                              float* __restrict__ outp) {
  __shared__ u16 lA[2][128 * 32];
  __shared__ u16 lB[2][128 * 32];
  const int tid = threadIdx.x;
  const int brow = blockIdx.y * 128, bcol = blockIdx.x * 128;
  const int lane = tid & 63, w = tid >> 6;
  const int wr = w >> 1, wc = w & 1;
  const int fr = lane & 15, fq = lane >> 4;
  f32x4 acc[4][4] = {};

  auto stageg = [&](int ks, int bb) {
#pragma unroll
    for (int it = 0; it < 2; ++it) {
      int chunk = tid + it * 256;
      int row = chunk >> 2;
      int colb = (chunk & 3) * 8;
      gload16(A  + (size_t)(brow + row) * 1024 + ks * 32 + colb, &lA[bb][chunk * 8]);
      gload16(Bw + (size_t)(bcol + row) * 1024 + ks * 32 + colb, &lB[bb][chunk * 8]);
    }
  };

  float bvr[4];
#pragma unroll
  for (int n = 0; n < 4; ++n) bvr[n] = bias[bcol + wc * 64 + n * 16 + fr];

  stageg(0, 0);
  WAIT_VM0();
  __builtin_amdgcn_s_barrier();

  for (int kk = 0; kk < 32; ++kk) {
    const int cur = kk & 1;
    if (kk + 1 < 32) { stageg(kk + 1, cur ^ 1); WAIT_VM4(); }
    else             { WAIT_VM0(); }
    __builtin_amdgcn_s_barrier();
    __builtin_amdgcn_sched_barrier(0);

    bf16x8 af[4], bfr[4];
#pragma unroll
    for (int m = 0; m < 4; ++m) af[m]  = *(const bf16x8*)&lA[cur][(wr * 64 + m * 16 + fr) * 32 + fq * 8];
#pragma unroll
    for (int n = 0; n < 4; ++n) bfr[n] = *(const bf16x8*)&lB[cur][(wc * 64 + n * 16 + fr) * 32 + fq * 8];
    __builtin_amdgcn_s_setprio(1);
#pragma unroll
    for (int m = 0; m < 4; ++m)
#pragma unroll
      for (int n = 0; n < 4; ++n)
        acc[m][n] = __builtin_amdgcn_mfma_f32_16x16x32_bf16(af[m], bfr[n], acc[m][n], 0, 0, 0);
    __builtin_amdgcn_s_setprio(0);

    WAIT_LGKM0();
    __builtin_amdgcn_s_barrier();
  }

#pragma unroll
  for (int m = 0; m < 4; ++m) {
#pragma unroll
    for (int n = 0; n < 4; ++n) {
      int colg = bcol + wc * 64 + n * 16 + fr;
#pragma unroll
      for (int j = 0; j < 4; ++j) {
        int rowg = brow + wr * 64 + m * 16 + fq * 4 + j;
        outp[(size_t)rowg * 1024 + colg] = acc[m][n][j] + bvr[n];
      }
    }
  }
}

// ---------------- causal flash attention: LDS K/V, counted-vmcnt pipeline ----
// Q,K: [NH=32][2048][64] bf16 (Q pre-scaled); V^T: [NH][64][2048] bf16.
// Block = one head, 128 q-rows (4 waves x 32), chunk of <=16 KV-tiles.
// Period = 2 KV-tiles (8KB K + 8KB V per buffer, double-buffered = 32KB LDS).
// Raw s_barrier + s_waitcnt vmcnt(4): prefetch stays in flight across barrier.
// XCD-bijective block swizzle: vbid=(bid%8)*160+bid/8 -> each head's 40 jobs
// (and its 512KB K/V) pin to one XCD's L2.
// Jobs/head = 40: c[] = {0,16,28,36,40}. Partials: acc bf16 [job][128q][64d].
__global__ __launch_bounds__(256) void attn_part(const u16* __restrict__ Qp,
                                                 const u16* __restrict__ Kp,
                                                 const u16* __restrict__ Vt,
                                                 u16* __restrict__ accP,
                                                 float* __restrict__ mP,
                                                 float* __restrict__ lP) {
  __shared__ u16 lK[2][4096];   // 2 x (64 rows x 128B), rows XOR-swizzled
  __shared__ u16 lV[2][4096];   // 2 x (2 subtiles x 32 lrows x 128B)
  const int tid = threadIdx.x;
  const int lane = tid & 63, w = tid >> 6;
  const int bid = (int)blockIdx.x;
  const int vbid = (bid & 7) * 160 + (bid >> 3);   // [0,1280) bijective
  const int nh = vbid / 40;
  const int j = vbid - nh * 40;
  int p, t;
  if (j < 16)      { p = 0; t = j; }
  else if (j < 28) { p = 1; t = 4 + (j - 16); }
  else if (j < 36) { p = 2; t = 8 + (j - 28); }
  else             { p = 3; t = 12 + (j - 36); }
  const int P0 = p * 8;                       // periods of 2 tiles (64 pos)
  const int P1 = min(P0 + 8, 2 * (t + 1));
  const int col = lane & 31, hi = lane >> 5;
  const u16* Q = Qp + (size_t)nh * 2048 * 64;
  const u16* K = Kp + (size_t)nh * 2048 * 64;
  const u16* V = Vt + (size_t)nh * 64 * 2048;
  const int qbase = t * 128 + w * 32;
  const int q = qbase + col;
  const int swz = (col & 7) << 4;             // read-side swizzle (bytes)

  auto stage = [&](int pp, int bb) {
#pragma unroll
    for (int it = 0; it < 2; ++it) {
      int c = tid + it * 256;                 // 16B chunk id, [0,512)
      int kr = c >> 3;                        // K row in [0,64)
      int kin = ((c & 7) * 16) ^ ((kr & 7) << 4);
      gload16(K + (size_t)(pp * 64 + kr) * 64 + (kin >> 1), &lK[bb][c * 8]);
      int tt = c >> 8, cc = c & 255;          // V subtile + chunk
      int lr = cc >> 3;
      int vin = ((cc & 7) * 16) ^ ((lr & 7) << 4);
      int vd = lr + ((vin >> 6) << 5);
      gload16(V + (size_t)vd * 2048 + pp * 64 + tt * 32 + ((vin & 63) >> 1),
              &lV[bb][c * 8]);
    }
  };

  bf16x8 qf[4];
#pragma unroll
  for (int ks = 0; ks < 4; ++ks) qf[ks] = *(const bf16x8*)&Q[(size_t)q * 64 + ks * 16 + hi * 8];

  f32x16 acc0 = {}, acc1 = {};   // out^T tiles: d in [0,32) and [32,64)
  float mrow = -1e30f, lsum = 0.f;

  stage(P0, 0);
  WAIT_VM0();
  __builtin_amdgcn_s_barrier();

  for (int pp = P0; pp < P1; ++pp) {
    const int buf = (pp - P0) & 1;
    if (pp + 1 < P1) { stage(pp + 1, buf ^ 1); WAIT_VM4(); }
    else             { WAIT_VM0(); }
    __builtin_amdgcn_s_barrier();
    __builtin_amdgcn_sched_barrier(0);

#pragma unroll
    for (int tt = 0; tt < 2; ++tt) {
      const int s0 = pp * 64 + tt * 32;
      if (s0 > qbase) continue;               // fully masked (wave-uniform)
      f32x16 sc = {};
      __builtin_amdgcn_s_setprio(1);
#pragma unroll
      for (int ks = 0; ks < 4; ++ks) {
        bf16x8 kf = *(const bf16x8*)&lK[buf][(tt * 32 + col) * 64 + (((ks * 32 + hi * 16) ^ swz) >> 1)];
        sc = __builtin_amdgcn_mfma_f32_32x32x16_bf16(kf, qf[ks], sc, 0, 0, 0);
      }
      __builtin_amdgcn_s_setprio(0);
      float pr[16];
      float pmax = -1e30f;
      if (s0 == qbase) {                      // diagonal tile: apply mask
#pragma unroll
        for (int r = 0; r < 16; ++r) {
          int sr = (r & 3) + 8 * (r >> 2) + 4 * hi;
          float v = (sr > col) ? -1e30f : sc[r];
          pr[r] = v;
          pmax = fmaxf(pmax, v);
        }
      } else {                                // interior tile: no mask
#pragma unroll
        for (int r = 0; r < 16; ++r) { pr[r] = sc[r]; pmax = fmaxf(pmax, sc[r]); }
      }
      pmax = fmaxf(pmax, __shfl_xor(pmax, 32));
      // defer-max: rescale only when running max grew by >8 (base-2 units)
      if (!__all(pmax <= mrow + 8.f)) {
        float mnew = fmaxf(mrow, pmax);
        float alpha = exp2f(mrow - mnew);
#pragma unroll
        for (int r = 0; r < 16; ++r) { acc0[r] *= alpha; acc1[r] *= alpha; }
        lsum *= alpha;
        mrow = mnew;
      }
      float ps = 0.f;
#pragma unroll
      for (int r = 0; r < 16; ++r) { float pv = exp2f(pr[r] - mrow); pr[r] = pv; ps += pv; }
      ps += __shfl_xor(ps, 32);
      lsum += ps;

      // Build PV B-operand (P^T as s x q), exchanging halves with lane^32
#pragma unroll
      for (int ks = 0; ks < 2; ++ks) {
        u32 A0 = cvtpk(pr[8 * ks + 0], pr[8 * ks + 1]);
        u32 A1 = cvtpk(pr[8 * ks + 2], pr[8 * ks + 3]);
        u32 B0 = cvtpk(pr[8 * ks + 4], pr[8 * ks + 5]);
        u32 B1 = cvtpk(pr[8 * ks + 6], pr[8 * ks + 7]);
        u32 t0 = __shfl_xor(hi ? A0 : B0, 32);
        u32 t1 = __shfl_xor(hi ? A1 : B1, 32);
        union { u32 u[4]; bf16x8 v; } pf;
        pf.u[0] = hi ? t0 : A0;
        pf.u[1] = hi ? t1 : A1;
        pf.u[2] = hi ? B0 : t0;
        pf.u[3] = hi ? B1 : t1;
        bf16x8 vf0 = *(const bf16x8*)&lV[buf][tt * 2048 + col * 64 + (((ks * 32 + hi * 16) ^ swz) >> 1)];
        bf16x8 vf1 = *(const bf16x8*)&lV[buf][tt * 2048 + col * 64 + (((64 + ks * 32 + hi * 16) ^ swz) >> 1)];
        __builtin_amdgcn_s_setprio(1);
        acc0 = __builtin_amdgcn_mfma_f32_32x32x16_bf16(vf0, pf.v, acc0, 0, 0, 0);
        acc1 = __builtin_amdgcn_mfma_f32_32x32x16_bf16(vf1, pf.v, acc1, 0, 0, 0);
        __builtin_amdgcn_s_setprio(0);
      }
    }

    WAIT_LGKM0();
    __builtin_amdgcn_s_barrier();
  }

  // write unnormalized partial: acc [vbid][q_local][d], m/l [vbid][q_local]
  const int ql = w * 32 + col;
  u16* base = accP + (size_t)vbid * 8192 + ql * 64;
#pragma unroll
  for (int rp = 0; rp < 8; ++rp) {
    int r = rp * 2;
    int d = (r & 3) + 8 * (r >> 2) + 4 * hi;
    *(u32*)&base[d]      = packbf(acc0[r], acc0[r + 1]);
    *(u32*)&base[32 + d] = packbf(acc1[r], acc1[r + 1]);
  }
  if (hi == 0) {
    mP[vbid * 128 + ql] = mrow;
    lP[vbid * 128 + ql] = lsum;
  }
}

// ---------------- combine up-to-4 partials per 128-row q-tile ----------------
// attn out: [N][2048][1024] bf16 (head-concat layout for the out projection)
__global__ void combineN(const u16* __restrict__ accP, const float* __restrict__ mP,
                         const float* __restrict__ lP, u16* __restrict__ at) {
  const int t = blockIdx.x >> 2;             // [0,16) q-tile of 128 rows
  const int seg = blockIdx.x & 3;            // 32-row segment
  const int nh = blockIdx.y;                 // [0,32)
  const int ql = seg * 32 + (threadIdx.x >> 3);   // [0,128)
  const int d0 = (threadIdx.x & 7) * 8;      // [0,64) step 8
  const int np = (t >> 2) + 1;               // parts: 1..4
  // slot(p) = nh*40 + c[p] + (t - 4p), c = {0,16,28,36}
  const int s0 = nh * 40 + t;
  const int s1 = nh * 40 + 16 + (t - 4);
  const int s2 = nh * 40 + 28 + (t - 8);
  const int s3 = nh * 40 + 36 + (t - 12);

  float m = mP[s0 * 128 + ql];
  if (np > 1) m = fmaxf(m, mP[s1 * 128 + ql]);
  if (np > 2) m = fmaxf(m, mP[s2 * 128 + ql]);
  if (np > 3) m = fmaxf(m, mP[s3 * 128 + ql]);
  float w0 = exp2f(mP[s0 * 128 + ql] - m);
  float w1 = (np > 1) ? exp2f(mP[s1 * 128 + ql] - m) : 0.f;
  float w2 = (np > 2) ? exp2f(mP[s2 * 128 + ql] - m) : 0.f;
  float w3 = (np > 3) ? exp2f(mP[s3 * 128 + ql] - m) : 0.f;
  float l = lP[s0 * 128 + ql] * w0;
  if (np > 1) l += lP[s1 * 128 + ql] * w1;
  if (np > 2) l += lP[s2 * 128 + ql] * w2;
  if (np > 3) l += lP[s3 * 128 + ql] * w3;
  const float inv = 1.f / l;
  w0 *= inv; w1 *= inv; w2 *= inv; w3 *= inv;

  float o[8] = {};
  {
    const bf16x8 a = *(const bf16x8*)&accP[(size_t)s0 * 8192 + ql * 64 + d0];
#pragma unroll
    for (int k = 0; k < 8; ++k) o[k] += bf2f((u16)a[k]) * w0;
  }
  if (np > 1) {
    const bf16x8 a = *(const bf16x8*)&accP[(size_t)s1 * 8192 + ql * 64 + d0];
#pragma unroll
    for (int k = 0; k < 8; ++k) o[k] += bf2f((u16)a[k]) * w1;
  }
  if (np > 2) {
    const bf16x8 a = *(const bf16x8*)&accP[(size_t)s2 * 8192 + ql * 64 + d0];
#pragma unroll
    for (int k = 0; k < 8; ++k) o[k] += bf2f((u16)a[k]) * w2;
  }
  if (np > 3) {
    const bf16x8 a = *(const bf16x8*)&accP[(size_t)s3 * 8192 + ql * 64 + d0];
#pragma unroll
    for (int k = 0; k < 8; ++k) o[k] += bf2f((u16)a[k]) * w3;
  }

  const int nb = nh >> 4, h = nh & 15;
  u16* op = &at[((size_t)(nb * 2048 + t * 128 + ql)) * 1024 + h * 64 + d0];
#pragma unroll
  for (int jj = 0; jj < 4; ++jj)
    *(u32*)&op[2 * jj] = packbf(o[2 * jj], o[2 * jj + 1]);
}

// -----------------------------------------------------------------------------
extern "C" void kernel_launch(void* const* d_in, const int* in_sizes, int n_in,
                              void* d_out, int out_size, void* d_ws, size_t ws_size,
                              hipStream_t stream) {
  const float* queries = (const float*)d_in[0];
  const float* keys    = (const float*)d_in[1];
  const float* values  = (const float*)d_in[2];
  const float* Wq = (const float*)d_in[3]; const float* bq = (const float*)d_in[4];
  const float* Wk = (const float*)d_in[5]; const float* bk = (const float*)d_in[6];
  const float* Wv = (const float*)d_in[7]; const float* bv = (const float*)d_in[8];
  const float* Wo = (const float*)d_in[9]; const float* bo = (const float*)d_in[10];
  float* out = (float*)d_out;
  char* ws = (char*)d_ws;

  const size_t MB = 1u << 20;
  u16* xq  = (u16*)(ws + 0 * MB);    // 8 MB (reused as attn output `at`)
  u16* xk  = (u16*)(ws + 8 * MB);
  u16* xv  = (u16*)(ws + 16 * MB);
  u16* wqb = (u16*)(ws + 24 * MB);
  u16* wkb = (u16*)(ws + 26 * MB);
  u16* wvb = (u16*)(ws + 28 * MB);
  u16* wob = (u16*)(ws + 30 * MB);   // LIVE until gemm_o
  u16* qp  = (u16*)(ws + 32 * MB);
  u16* kp  = (u16*)(ws + 40 * MB);
  u16* vt  = (u16*)(ws + 48 * MB);
  u16* at  = xq;                            // attn out reuses xq
  // split-KV partials: 1280 slots x 16 KB = 20 MB at [8,28); m/l 640 KB each
  u16*   accP = (u16*)(ws + 8 * MB);
  float* mPp  = (float*)(ws + 28 * MB);
  float* lPp  = (float*)(ws + 28 * MB + 1280 * 128 * sizeof(float));

  // fp32 -> bf16 (all tensors, one launch)
  cvt7<<<dim3(4096, 7), 256, 0, stream>>>(queries, keys, values, Wq, Wk, Wv, Wo,
                                          xq, xk, xv, wqb, wkb, wvb, wob);
  // Q/K/V projections, one batched launch (768 blocks = 3/CU)
  gemm3<<<dim3(8, 32, 3), 256, 0, stream>>>(xq, xk, xv, wqb, wkb, wvb,
                                            bq, bk, bv, qp, kp, vt);
  // attention partials: 1280 blocks (4 waves, LDS K/V, counted-vmcnt pipeline)
  attn_part<<<1280, 256, 0, stream>>>(qp, kp, vt, accP, mPp, lPp);
  combineN<<<dim3(64, 32), 256, 0, stream>>>(accP, mPp, lPp, at);
  // output projection
  gemm_o<<<dim3(8, 32), 256, 0, stream>>>(at, wob, bo, out);
}